// Round 1
// baseline (704.072 us; speedup 1.0000x reference)
//
#include <hip/hip_runtime.h>

// SNN LIF, T=1000, B=8192, IN=4, HID=10, OUT=3.
// Strategy: 4 lanes (one quad) per batch element -> 32768 threads = 512 waves.
// Each lane owns 3 (zero-padded to 12) layer-1 neurons; layer-2 current is
// quad-reduced via DPP quad_perm adds (VALU-rate, no LDS). reset_t == spk_{t-1}
// so the reset term is folded into the bias. x prefetched one step ahead.

#define T_STEPS 1000
#define BATCH   8192
#define IN_DIM  4
#define HID     10
#define OUT_DIM 3
#define BETA    0.95f
#define THR     1.0f

__device__ __forceinline__ float quad_sum(float v) {
    // sum across the 4 lanes of each quad: xor1 then xor2 via DPP quad_perm
    int i = __builtin_bit_cast(int, v);
    int a = __builtin_amdgcn_update_dpp(0, i, 0xB1 /*quad_perm(1,0,3,2)*/, 0xF, 0xF, true);
    v += __builtin_bit_cast(float, a);
    i = __builtin_bit_cast(int, v);
    int b = __builtin_amdgcn_update_dpp(0, i, 0x4E /*quad_perm(2,3,0,1)*/, 0xF, 0xF, true);
    v += __builtin_bit_cast(float, b);
    return v;
}

__global__ __launch_bounds__(256)
void snn_lif_kernel(const float* __restrict__ x,
                    const float* __restrict__ W1,
                    const float* __restrict__ b1,
                    const float* __restrict__ W2,
                    const float* __restrict__ b2,
                    float* __restrict__ out)
{
    const int tid = blockIdx.x * blockDim.x + threadIdx.x;   // 0..32767
    const int bidx = tid >> 2;     // batch element
    const int sub  = tid & 3;      // lane within quad

    // Per-lane weights: neurons h = sub*3 + j (j<3), zero-padded for h >= 10.
    float w1r[3][4], b1r[3], w2r[3][3];
    #pragma unroll
    for (int j = 0; j < 3; ++j) {
        const int h = sub * 3 + j;
        const bool valid = (h < HID);
        #pragma unroll
        for (int i = 0; i < IN_DIM; ++i)
            w1r[j][i] = valid ? W1[h * IN_DIM + i] : 0.0f;
        b1r[j] = valid ? b1[h] : 0.0f;
        #pragma unroll
        for (int o = 0; o < OUT_DIM; ++o)
            w2r[o][j] = valid ? W2[o * HID + h] : 0.0f;
    }
    const float b2r0 = b2[0], b2r1 = b2[1], b2r2 = b2[2];
    float b2r[3] = {b2r0, b2r1, b2r2};

    float mem1[3] = {0.f, 0.f, 0.f};
    float spk1[3] = {0.f, 0.f, 0.f};   // spike == next step's reset
    float mem2[3] = {0.f, 0.f, 0.f};
    float spk2[3] = {0.f, 0.f, 0.f};

    const float4* xp = reinterpret_cast<const float4*>(x) + bidx;
    float* sp = out + (size_t)bidx * OUT_DIM;                       // spk2 rec
    float* mp = sp + (size_t)T_STEPS * BATCH * OUT_DIM;             // mem2 rec

    float4 xv = *xp;
    for (int t = 0; t < T_STEPS; ++t) {
        // prefetch next timestep's x (clamped pointer on last iter)
        const float4* xnp = xp + ((t + 1 < T_STEPS) ? BATCH : 0);
        float4 xn = *xnp;

        // ---- layer 1 (3 neurons per lane) ----
        #pragma unroll
        for (int j = 0; j < 3; ++j) {
            float cur = (b1r[j] - spk1[j])
                      + w1r[j][0] * xv.x + w1r[j][1] * xv.y
                      + w1r[j][2] * xv.z + w1r[j][3] * xv.w;
            mem1[j] = BETA * mem1[j] + cur;
            spk1[j] = (mem1[j] > THR) ? 1.0f : 0.0f;
        }

        // ---- layer 2: partial currents, quad reduce, LIF update ----
        #pragma unroll
        for (int o = 0; o < OUT_DIM; ++o) {
            float p = w2r[o][0] * spk1[0] + w2r[o][1] * spk1[1]
                    + w2r[o][2] * spk1[2];
            float cur2 = quad_sum(p) + (b2r[o] - spk2[o]);
            mem2[o] = BETA * mem2[o] + cur2;
            spk2[o] = (mem2[o] > THR) ? 1.0f : 0.0f;
        }

        if (sub == 0) {
            sp[0] = spk2[0]; sp[1] = spk2[1]; sp[2] = spk2[2];
            mp[0] = mem2[0]; mp[1] = mem2[1]; mp[2] = mem2[2];
        }
        sp += BATCH * OUT_DIM;
        mp += BATCH * OUT_DIM;
        xp = xnp;
        xv = xn;
    }
}

extern "C" void kernel_launch(void* const* d_in, const int* in_sizes, int n_in,
                              void* d_out, int out_size, void* d_ws, size_t ws_size,
                              hipStream_t stream) {
    const float* x  = (const float*)d_in[0];
    const float* W1 = (const float*)d_in[1];
    const float* b1 = (const float*)d_in[2];
    const float* W2 = (const float*)d_in[3];
    const float* b2 = (const float*)d_in[4];
    float* out = (float*)d_out;

    const int threads = BATCH * 4;          // 4 lanes per batch element
    const int block = 256;
    const int grid = threads / block;       // 128 blocks
    snn_lif_kernel<<<grid, block, 0, stream>>>(x, W1, b1, W2, b2, out);
}

// Round 6
// 687.595 us; speedup vs baseline: 1.0240x; 1.0240x over previous
//
#include <hip/hip_runtime.h>

// SNN LIF, T=1000, B=8192, IN=4, HID=10, OUT=3.
// Strategy: 4 lanes (one quad) per batch element -> 32768 threads = 512 waves.
// Each lane owns 3 (zero-padded to 12) layer-1 neurons; layer-2 current is
// quad-reduced via DPP quad_perm adds (VALU-rate, no LDS). reset_t == spk_{t-1}
// so the reset term is folded into the bias. x prefetched one step ahead.
//
// NOTE (rounds 2-5): this kernel's DEVICE CODE is byte-identical to the
// round-1 version, which is the only binary verified to match the np
// reference's spike trajectory exactly (absmax 0.0156, zero spike flips).
// Four attempts to restructure the arithmetic (deeper pipelining, explicit
// fma placement, BLAS-order reconstruction) each produced >=1 spike flip vs
// the reference (errors 0.297 / 1.0 > threshold 0.1775). DO NOT alter any
// expression, loop structure, or launch_bounds in the kernel body.
// Host-side launch geometry changed 128x256 -> 512x64: tid mapping identical
// (blockIdx.x*blockDim.x+threadIdx.x), device codegen untouched; spreads the
// 512 waves over all 256 CUs (2 single-wave blocks/CU) for doubled per-CU
// memory-queue parallelism on this latency-bound binary.

#define T_STEPS 1000
#define BATCH   8192
#define IN_DIM  4
#define HID     10
#define OUT_DIM 3
#define BETA    0.95f
#define THR     1.0f

__device__ __forceinline__ float quad_sum(float v) {
    // sum across the 4 lanes of each quad: xor1 then xor2 via DPP quad_perm
    int i = __builtin_bit_cast(int, v);
    int a = __builtin_amdgcn_update_dpp(0, i, 0xB1 /*quad_perm(1,0,3,2)*/, 0xF, 0xF, true);
    v += __builtin_bit_cast(float, a);
    i = __builtin_bit_cast(int, v);
    int b = __builtin_amdgcn_update_dpp(0, i, 0x4E /*quad_perm(2,3,0,1)*/, 0xF, 0xF, true);
    v += __builtin_bit_cast(float, b);
    return v;
}

__global__ __launch_bounds__(256)
void snn_lif_kernel(const float* __restrict__ x,
                    const float* __restrict__ W1,
                    const float* __restrict__ b1,
                    const float* __restrict__ W2,
                    const float* __restrict__ b2,
                    float* __restrict__ out)
{
    const int tid = blockIdx.x * blockDim.x + threadIdx.x;   // 0..32767
    const int bidx = tid >> 2;     // batch element
    const int sub  = tid & 3;      // lane within quad

    // Per-lane weights: neurons h = sub*3 + j (j<3), zero-padded for h >= 10.
    float w1r[3][4], b1r[3], w2r[3][3];
    #pragma unroll
    for (int j = 0; j < 3; ++j) {
        const int h = sub * 3 + j;
        const bool valid = (h < HID);
        #pragma unroll
        for (int i = 0; i < IN_DIM; ++i)
            w1r[j][i] = valid ? W1[h * IN_DIM + i] : 0.0f;
        b1r[j] = valid ? b1[h] : 0.0f;
        #pragma unroll
        for (int o = 0; o < OUT_DIM; ++o)
            w2r[o][j] = valid ? W2[o * HID + h] : 0.0f;
    }
    const float b2r0 = b2[0], b2r1 = b2[1], b2r2 = b2[2];
    float b2r[3] = {b2r0, b2r1, b2r2};

    float mem1[3] = {0.f, 0.f, 0.f};
    float spk1[3] = {0.f, 0.f, 0.f};   // spike == next step's reset
    float mem2[3] = {0.f, 0.f, 0.f};
    float spk2[3] = {0.f, 0.f, 0.f};

    const float4* xp = reinterpret_cast<const float4*>(x) + bidx;
    float* sp = out + (size_t)bidx * OUT_DIM;                       // spk2 rec
    float* mp = sp + (size_t)T_STEPS * BATCH * OUT_DIM;             // mem2 rec

    float4 xv = *xp;
    for (int t = 0; t < T_STEPS; ++t) {
        // prefetch next timestep's x (clamped pointer on last iter)
        const float4* xnp = xp + ((t + 1 < T_STEPS) ? BATCH : 0);
        float4 xn = *xnp;

        // ---- layer 1 (3 neurons per lane) ----
        #pragma unroll
        for (int j = 0; j < 3; ++j) {
            float cur = (b1r[j] - spk1[j])
                      + w1r[j][0] * xv.x + w1r[j][1] * xv.y
                      + w1r[j][2] * xv.z + w1r[j][3] * xv.w;
            mem1[j] = BETA * mem1[j] + cur;
            spk1[j] = (mem1[j] > THR) ? 1.0f : 0.0f;
        }

        // ---- layer 2: partial currents, quad reduce, LIF update ----
        #pragma unroll
        for (int o = 0; o < OUT_DIM; ++o) {
            float p = w2r[o][0] * spk1[0] + w2r[o][1] * spk1[1]
                    + w2r[o][2] * spk1[2];
            float cur2 = quad_sum(p) + (b2r[o] - spk2[o]);
            mem2[o] = BETA * mem2[o] + cur2;
            spk2[o] = (mem2[o] > THR) ? 1.0f : 0.0f;
        }

        if (sub == 0) {
            sp[0] = spk2[0]; sp[1] = spk2[1]; sp[2] = spk2[2];
            mp[0] = mem2[0]; mp[1] = mem2[1]; mp[2] = mem2[2];
        }
        sp += BATCH * OUT_DIM;
        mp += BATCH * OUT_DIM;
        xp = xnp;
        xv = xn;
    }
}

extern "C" void kernel_launch(void* const* d_in, const int* in_sizes, int n_in,
                              void* d_out, int out_size, void* d_ws, size_t ws_size,
                              hipStream_t stream) {
    const float* x  = (const float*)d_in[0];
    const float* W1 = (const float*)d_in[1];
    const float* b1 = (const float*)d_in[2];
    const float* W2 = (const float*)d_in[3];
    const float* b2 = (const float*)d_in[4];
    float* out = (float*)d_out;

    const int threads = BATCH * 4;     // 4 lanes per batch element
    const int block = 64;              // single-wave blocks -> spread over all 256 CUs
    const int grid = threads / block;  // 512 blocks (tid mapping identical to 128x256)
    snn_lif_kernel<<<grid, block, 0, stream>>>(x, W1, b1, W2, b2, out);
}